// Round 7
// baseline (332.817 us; speedup 1.0000x reference)
//
#include <hip/hip_runtime.h>
#include <hip/hip_cooperative_groups.h>
#include <math.h>

namespace cg = cooperative_groups;

#define N_NODES 50000
#define E_RAW 800000
#define E_TOT 850000
#define NEG_SLOPE 0.2f
#define G1_BLOCKS ((N_NODES + 63) / 64)          // gemm1 MFMA part: BM=64, 256 thr
#define NBUCK 391                                // ceil(50000 / 128) col-buckets
#define EPB 2048                                 // edges per partition block
#define PBLK ((E_TOT + EPB - 1) / EPB)           // 416 partition blocks

typedef __attribute__((ext_vector_type(8))) short bf16x8;
typedef __attribute__((ext_vector_type(4))) float f32x4;

__device__ __forceinline__ float lrelu(float a) { return a > 0.f ? a : NEG_SLOPE * a; }

__device__ __forceinline__ unsigned f2bf(float f) {
    unsigned u = __float_as_uint(f);
    return (u + 0x7fff + ((u >> 16) & 1)) >> 16;
}
__device__ __forceinline__ unsigned pack2(float a, float b) {
    return f2bf(a) | (f2bf(b) << 16);
}
__device__ __forceinline__ float bflo(unsigned p) { return __uint_as_float(p << 16); }
__device__ __forceinline__ float bfhi(unsigned p) { return __uint_as_float(p & 0xffff0000u); }

// ---------------- prep (combined): W1^T bf16, Wc=(W2@headW)^T bf16, av=W2@attn2 halves ----
__global__ void k_prep(const float* __restrict__ W1, const float* __restrict__ W2,
                       const float* __restrict__ attn2, const float* __restrict__ headW,
                       unsigned* __restrict__ Btg, unsigned* __restrict__ Wctg,
                       float* __restrict__ av) {
    int b = blockIdx.x, t = threadIdx.x;   // 193 blocks x 128 thr
    if (b < 128) {
        if (t < 64) Btg[b * 64 + t] = pack2(W1[(2 * t) * 128 + b], W1[(2 * t + 1) * 128 + b]);
    } else if (b < 192) {
        if (t < 64) {
            int f = b - 128, q = t;
            float s0 = 0.f, s1 = 0.f;
            for (int j = 0; j < 64; ++j) {
                float hw = headW[j * 64 + f];
                s0 = fmaf(W2[(2 * q) * 64 + j], hw, s0);
                s1 = fmaf(W2[(2 * q + 1) * 64 + j], hw, s1);
            }
            Wctg[f * 64 + q] = pack2(s0, s1);
        }
    } else {
        int k = t;                          // 0..127
        float sl = 0.f, sr = 0.f;
        for (int j = 0; j < 64; ++j) {
            float w = W2[k * 64 + j];
            sl = fmaf(w, attn2[j], sl);
            sr = fmaf(w, attn2[64 + j], sr);
        }
        av[k] = sl; av[128 + k] = sr;
    }
}

// ---------------- FUSED: gemm1 MFMA (blocks < G1) || P1 bucket histogram ----------------
__global__ void k_gemm1_p1(const float* __restrict__ A, const unsigned* __restrict__ Btg,
                           const float* __restrict__ aux, uint2* __restrict__ C,
                           float* __restrict__ es, float* __restrict__ ed,
                           const int* __restrict__ ei, int* __restrict__ hist2d) {
    __shared__ unsigned As[64 * 64];   // 16 KB (gemm tile; P1 reuses first 1.6KB as int hist)
    if (blockIdx.x >= G1_BLOCKS) {
        // ---- P1 body: bucket histogram, LDS atomics only ----
        int blk = blockIdx.x - G1_BLOCKS;
        int* h = (int*)As;
        for (int i = threadIdx.x; i < NBUCK; i += 256) h[i] = 0;
        __syncthreads();
        int base = blk * EPB;
        for (int i = threadIdx.x; i < EPB; i += 256) {
            int e = base + i;
            if (e >= E_TOT) break;
            int col = (e < E_RAW) ? ei[E_RAW + e] : (e - E_RAW);
            atomicAdd(&h[col >> 7], 1);
        }
        __syncthreads();
        for (int i = threadIdx.x; i < NBUCK; i += 256) hist2d[i * PBLK + blk] = h[i];
        return;
    }
    // ---- gemm1 MFMA body ----
    int t = threadIdx.x;
    int m0 = blockIdx.x * 64;
    int rows = min(64, N_NODES - m0);
    const float4* A4 = (const float4*)(A + (size_t)m0 * 128);
    for (int i = t; i < rows * 32; i += 256) {
        int row = i >> 5, k4 = i & 31;
        float4 v = A4[i];
        int byte = (k4 * 8) ^ ((row & 7) << 4);
        unsigned* p = &As[row * 64 + (byte >> 2)];
        p[0] = pack2(v.x, v.y);
        p[1] = pack2(v.z, v.w);
    }
    __syncthreads();
    int lane = t & 63, wave = t >> 6;
    int r15 = lane & 15, g = lane >> 4;
    int arow = wave * 16 + r15;
    f32x4 acc[8];
#pragma unroll
    for (int i = 0; i < 8; ++i) acc[i] = (f32x4){0.f, 0.f, 0.f, 0.f};
    const char* Abase = (const char*)As + arow * 256;
    int swz = (arow & 7) << 4;
    const char* Bbase = (const char*)Btg;
#pragma unroll
    for (int s = 0; s < 4; ++s) {
        bf16x8 xf = *(const bf16x8*)(Abase + ((64 * s + 16 * g) ^ swz));
#pragma unroll
        for (int tt = 0; tt < 8; ++tt) {
            bf16x8 wf = *(const bf16x8*)(Bbase + ((16 * tt + r15) * 256 + 64 * s + 16 * g));
            acc[tt] = __builtin_amdgcn_mfma_f32_16x16x32_bf16(wf, xf, acc[tt], 0, 0, 0);
        }
    }
    int grow = m0 + arow;
    bool valid = (arow < rows);
    if (valid) {
        uint2* C2 = C + (size_t)grow * 32;
#pragma unroll
        for (int tt = 0; tt < 8; ++tt) {
            uint2 v; v.x = pack2(acc[tt][0], acc[tt][1]); v.y = pack2(acc[tt][2], acc[tt][3]);
            C2[4 * tt + g] = v;
        }
    }
    float ps0 = 0.f, ps1 = 0.f, ps2 = 0.f, ps3 = 0.f;
    float pd0 = 0.f, pd1 = 0.f, pd2 = 0.f, pd3 = 0.f;
#pragma unroll
    for (int tt = 0; tt < 8; ++tt) {
        int h = tt >> 1;
        int fin = 16 * (tt & 1) + 4 * g;
        float4 alv = *(const float4*)(aux + h * 64 + fin);
        float4 arv = *(const float4*)(aux + h * 64 + 32 + fin);
        float s4 = acc[tt][0] * alv.x + acc[tt][1] * alv.y + acc[tt][2] * alv.z + acc[tt][3] * alv.w;
        float d4 = acc[tt][0] * arv.x + acc[tt][1] * arv.y + acc[tt][2] * arv.z + acc[tt][3] * arv.w;
        if (h == 0) { ps0 += s4; pd0 += d4; }
        else if (h == 1) { ps1 += s4; pd1 += d4; }
        else if (h == 2) { ps2 += s4; pd2 += d4; }
        else { ps3 += s4; pd3 += d4; }
    }
#pragma unroll
    for (int mask = 16; mask <= 32; mask <<= 1) {
        ps0 += __shfl_xor(ps0, mask); ps1 += __shfl_xor(ps1, mask);
        ps2 += __shfl_xor(ps2, mask); ps3 += __shfl_xor(ps3, mask);
        pd0 += __shfl_xor(pd0, mask); pd1 += __shfl_xor(pd1, mask);
        pd2 += __shfl_xor(pd2, mask); pd3 += __shfl_xor(pd3, mask);
    }
    if (valid) {
        float psg = (g == 0) ? ps0 : (g == 1) ? ps1 : (g == 2) ? ps2 : ps3;
        float pdg = (g == 0) ? pd0 : (g == 1) ? pd1 : (g == 2) ? pd2 : pd3;
        es[grow * 4 + g] = psg;
        ed[grow * 4 + g] = pdg;
    }
}

// ---------------- CSR (cooperative): p2a -> p3 -> p4 with grid.sync barriers ----------------
// Phase1 (b<NBUCK): scan hist2d rows -> off2d, bucktot.
// Phase2 (b<PBLK):  partition edges into bucket-grouped part[].
// Phase3 (b<NBUCK): per-bucket col histogram+scan -> off[], srcs[].
__global__ void k_csr(const int* __restrict__ ei, const int* __restrict__ hist2d,
                      int* __restrict__ off2d, int* __restrict__ bucktot,
                      unsigned* __restrict__ part, int* __restrict__ off,
                      unsigned short* __restrict__ srcs) {
    cg::grid_group grid = cg::this_grid();
    __shared__ int sh[512];
    __shared__ int hh[NBUCK];
    __shared__ int bb[NBUCK];
    __shared__ int s0sh, s1sh;
    int b = blockIdx.x, t = threadIdx.x;
    // ---- phase 1: p2a ----
    if (b < NBUCK) {
        int v = (t < PBLK) ? hist2d[b * PBLK + t] : 0;
        sh[t] = v;
        __syncthreads();
        for (int ofs = 1; ofs < 512; ofs <<= 1) {
            int u = (t >= ofs) ? sh[t - ofs] : 0;
            __syncthreads();
            sh[t] += u;
            __syncthreads();
        }
        if (t < PBLK) off2d[b * PBLK + t] = sh[t] - v;
        if (t == 511) bucktot[b] = sh[511];
    }
    grid.sync();
    // ---- phase 2: p3 ----
    if (b < PBLK) {
        int v = (t < NBUCK) ? bucktot[t] : 0;
        sh[t] = v;
        if (t < NBUCK) hh[t] = 0;
        __syncthreads();
        for (int ofs = 1; ofs < 512; ofs <<= 1) {
            int u = (t >= ofs) ? sh[t - ofs] : 0;
            __syncthreads();
            sh[t] += u;
            __syncthreads();
        }
        if (t < NBUCK) bb[t] = (sh[t] - v) + off2d[t * PBLK + b];
        __syncthreads();
        int base = b * EPB;
        for (int i = t; i < EPB; i += 512) {
            int e = base + i;
            if (e >= E_TOT) break;
            int col, src;
            if (e < E_RAW) { col = ei[E_RAW + e]; src = ei[e]; }
            else { col = src = e - E_RAW; }
            int bk = col >> 7;
            int lr = atomicAdd(&hh[bk], 1);
            part[bb[bk] + lr] = (unsigned)src | ((unsigned)(col & 127) << 16);
        }
    }
    grid.sync();
    // ---- phase 3: p4 ----
    if (b < NBUCK) {
        int v = (t < NBUCK) ? bucktot[t] : 0;
        sh[t] = v;
        if (t < 128) hh[t] = 0;
        __syncthreads();
        for (int ofs = 1; ofs < 512; ofs <<= 1) {
            int u = (t >= ofs) ? sh[t - ofs] : 0;
            __syncthreads();
            sh[t] += u;
            __syncthreads();
        }
        if (t == 0) { s1sh = sh[b]; s0sh = sh[b] - bucktot[b]; }
        __syncthreads();
        int s0 = s0sh, s1 = s1sh;
        for (int i = s0 + t; i < s1; i += 512) atomicAdd(&hh[part[i] >> 16], 1);
        __syncthreads();
        if (t == 0) {
            int acc = 0;
            for (int c = 0; c < 128; ++c) { bb[c] = acc; acc += hh[c]; }
        }
        __syncthreads();
        int colbase = b * 128, ncols = min(128, N_NODES - colbase);
        if (t < ncols) off[colbase + t] = s0 + bb[t];
        if (b == NBUCK - 1 && t == 0) off[N_NODES] = s1;
        if (t < 128) hh[t] = bb[t];    // cursors
        __syncthreads();
        for (int i = s0 + t; i < s1; i += 512) {
            unsigned u = part[i];
            int c = u >> 16;
            int slot = atomicAdd(&hh[c], 1);
            srcs[s0 + slot] = (unsigned short)(u & 0xffffu);
        }
    }
}

// ---------------- GEMMV MFMA: v2 = out1b(bf16) @ Wc, K=128, N=64 (no epilogue) ----------------
__global__ void k_gemmv(const unsigned* __restrict__ A, const unsigned* __restrict__ Wctg,
                        uint2* __restrict__ C) {
    __shared__ unsigned As[64 * 64];   // 16 KB: 64 rows x 128 bf16, swizzled
    int t = threadIdx.x;
    int m0 = blockIdx.x * 64;
    int rows = min(64, N_NODES - m0);
    const uint4* A4 = (const uint4*)(A + (size_t)m0 * 64);
    for (int i = t; i < rows * 16; i += 256) {
        int row = i >> 4, q = i & 15;
        uint4 v = A4[i];
        int byte = (q * 16) ^ ((row & 7) << 4);
        unsigned* p = &As[row * 64 + (byte >> 2)];
        p[0] = v.x; p[1] = v.y; p[2] = v.z; p[3] = v.w;
    }
    __syncthreads();
    int lane = t & 63, wave = t >> 6;
    int r15 = lane & 15, g = lane >> 4;
    int arow = wave * 16 + r15;
    f32x4 acc[4];
#pragma unroll
    for (int i = 0; i < 4; ++i) acc[i] = (f32x4){0.f, 0.f, 0.f, 0.f};
    const char* Abase = (const char*)As + arow * 256;
    int swz = (arow & 7) << 4;
    const char* Bbase = (const char*)Wctg;
#pragma unroll
    for (int s = 0; s < 4; ++s) {
        bf16x8 xf = *(const bf16x8*)(Abase + ((64 * s + 16 * g) ^ swz));
#pragma unroll
        for (int tt = 0; tt < 4; ++tt) {
            bf16x8 wf = *(const bf16x8*)(Bbase + ((16 * tt + r15) * 256 + 64 * s + 16 * g));
            acc[tt] = __builtin_amdgcn_mfma_f32_16x16x32_bf16(wf, xf, acc[tt], 0, 0, 0);
        }
    }
    int grow = m0 + arow;
    if (arow < rows) {
        uint2* C2 = C + (size_t)grow * 16;
#pragma unroll
        for (int tt = 0; tt < 4; ++tt) {
            uint2 v; v.x = pack2(acc[tt][0], acc[tt][1]); v.y = pack2(acc[tt][2], acc[tt][3]);
            C2[4 * tt + g] = v;
        }
    }
}

// ---------------- layer-1 fused softmax+aggregate + layer-2 score epilogue ----------------
// Latency-overlapped: row gathers (depend only on srcj) issue BEFORE the es-gather/exp
// chain, so the two ~500cy memory chains run in parallel instead of serially.
__global__ void k_agg1(const unsigned* __restrict__ h1b, const float* __restrict__ es,
                       const float* __restrict__ ed, const int* __restrict__ off,
                       const unsigned short* __restrict__ srcs, const float* __restrict__ av,
                       unsigned* __restrict__ out1,
                       float* __restrict__ e2s, float* __restrict__ e2d) {
    int n = blockIdx.x * (blockDim.x >> 6) + (threadIdx.x >> 6);
    int lane = threadIdx.x & 63;
    if (n >= N_NODES) return;
    int myh = lane & 3;           // head for w-compute phase
    int jj = lane >> 2;           // edge slot (0..15) for w-compute
    float edh = ed[n * 4 + myh];
    int s = off[n], e = off[n + 1];
    int l16 = lane & 15;          // feature block: features 8*l16 .. 8*l16+7
    int esub = lane >> 4;         // edge subgroup 0..3
    int hcL = l16 >> 2;           // head owning this lane's features
    float acc[8];
#pragma unroll
    for (int i = 0; i < 8; ++i) acc[i] = 0.f;
    float psum = 0.f;
    for (int base = s; base < e; base += 16) {
        int cnt = e - base;       // wave-uniform
        int srcj = 0;
        if (jj < cnt) srcj = srcs[base + jj];
        // 1) shuffle src indices and ISSUE the row gathers first
        int src4[4];
#pragma unroll
        for (int q = 0; q < 4; ++q) src4[q] = __shfl(srcj, (4 * q + esub) * 4);
        uint4 pv4[4];
#pragma unroll
        for (int q = 0; q < 4; ++q)
            pv4[q] = *((const uint4*)(h1b + (size_t)src4[q] * 64 + l16 * 4));
        // 2) es-gather + exp chain overlaps the row-gather latency
        float w = 0.f;
        if (jj < cnt) w = __expf(lrelu(es[srcj * 4 + myh] + edh));
        psum += w;
        float wv4[4];
#pragma unroll
        for (int q = 0; q < 4; ++q) wv4[q] = __shfl(w, (4 * q + esub) * 4 + hcL);
        // 3) FMAs
#pragma unroll
        for (int q = 0; q < 4; ++q) {
            float wv = wv4[q];
            acc[0] = fmaf(bflo(pv4[q].x), wv, acc[0]);
            acc[1] = fmaf(bfhi(pv4[q].x), wv, acc[1]);
            acc[2] = fmaf(bflo(pv4[q].y), wv, acc[2]);
            acc[3] = fmaf(bfhi(pv4[q].y), wv, acc[3]);
            acc[4] = fmaf(bflo(pv4[q].z), wv, acc[4]);
            acc[5] = fmaf(bfhi(pv4[q].z), wv, acc[5]);
            acc[6] = fmaf(bflo(pv4[q].w), wv, acc[6]);
            acc[7] = fmaf(bfhi(pv4[q].w), wv, acc[7]);
        }
    }
    // per-head softmax denom: sum over edge slots (bits 2-5), heads (bits 0-1) preserved
#pragma unroll
    for (int mask = 4; mask <= 32; mask <<= 1) psum += __shfl_xor(psum, mask);
    float inv = 1.f / __shfl(psum, hcL);
    // reduce the 4 edge-subgroups
#pragma unroll
    for (int i = 0; i < 8; ++i) {
        acc[i] += __shfl_xor(acc[i], 16);
        acc[i] += __shfl_xor(acc[i], 32);
    }
    float o[8];
#pragma unroll
    for (int i = 0; i < 8; ++i) o[i] = fmaxf(acc[i] * inv, 0.f);
    if (esub == 0) {
        uint4 ov;
        ov.x = pack2(o[0], o[1]);
        ov.y = pack2(o[2], o[3]);
        ov.z = pack2(o[4], o[5]);
        ov.w = pack2(o[6], o[7]);
        *((uint4*)(out1 + (size_t)n * 64 + l16 * 4)) = ov;
    }
    // layer-2 attention scores (all lanes hold full o for their 8 features)
    float4 vl0 = *(const float4*)(av + 8 * l16);
    float4 vl1 = *(const float4*)(av + 8 * l16 + 4);
    float4 vr0 = *(const float4*)(av + 128 + 8 * l16);
    float4 vr1 = *(const float4*)(av + 128 + 8 * l16 + 4);
    float pl = o[0] * vl0.x + o[1] * vl0.y + o[2] * vl0.z + o[3] * vl0.w
             + o[4] * vl1.x + o[5] * vl1.y + o[6] * vl1.z + o[7] * vl1.w;
    float pr = o[0] * vr0.x + o[1] * vr0.y + o[2] * vr0.z + o[3] * vr0.w
             + o[4] * vr1.x + o[5] * vr1.y + o[6] * vr1.z + o[7] * vr1.w;
#pragma unroll
    for (int mask = 1; mask <= 8; mask <<= 1) {
        pl += __shfl_xor(pl, mask);
        pr += __shfl_xor(pr, mask);
    }
    if (lane == 0) { e2s[n] = pl; e2d[n] = pr; }
}

// ---------------- layer-2 aggregate (final): gather v2b rows + bias -> out ----------------
// Same latency-overlap reorder as agg1.
__global__ void k_agg2f(const unsigned* __restrict__ v2b, const float* __restrict__ es,
                        const float* __restrict__ ed, const int* __restrict__ off,
                        const unsigned short* __restrict__ srcs,
                        const float* __restrict__ headb, float* __restrict__ outv) {
    int n = blockIdx.x * 4 + (threadIdx.x >> 6);   // grid is exactly N_NODES/4
    int lane = threadIdx.x & 63;
    float edv = ed[n];
    int s = off[n], e = off[n + 1];
    int l16 = lane & 15;          // feature block: features 4*l16 .. 4*l16+3
    int esub = lane >> 4;         // edge subgroup 0..3
    const uint2* gp = (const uint2*)v2b;
    float a0 = 0.f, a1 = 0.f, a2 = 0.f, a3 = 0.f, psum = 0.f;
    for (int base = s; base < e; base += 16) {
        int cnt = e - base;        // wave-uniform
        int srcj = 0;
        if (lane < 16 && lane < cnt) srcj = srcs[base + lane];
        int src4[4];
#pragma unroll
        for (int q = 0; q < 4; ++q) src4[q] = __shfl(srcj, 4 * q + esub);
        uint2 pv4[4];
#pragma unroll
        for (int q = 0; q < 4; ++q) pv4[q] = gp[(size_t)src4[q] * 16 + l16];
        float w = 0.f;
        if (lane < 16 && lane < cnt) w = __expf(lrelu(es[srcj] + edv));
        psum += w;
        float wv4[4];
#pragma unroll
        for (int q = 0; q < 4; ++q) wv4[q] = __shfl(w, 4 * q + esub);
#pragma unroll
        for (int q = 0; q < 4; ++q) {
            a0 = fmaf(bflo(pv4[q].x), wv4[q], a0);
            a1 = fmaf(bfhi(pv4[q].x), wv4[q], a1);
            a2 = fmaf(bflo(pv4[q].y), wv4[q], a2);
            a3 = fmaf(bfhi(pv4[q].y), wv4[q], a3);
        }
    }
#pragma unroll
    for (int mask = 1; mask <= 8; mask <<= 1) psum += __shfl_xor(psum, mask);
    float inv = 1.f / __shfl(psum, 0);
    a0 += __shfl_xor(a0, 16); a0 += __shfl_xor(a0, 32);
    a1 += __shfl_xor(a1, 16); a1 += __shfl_xor(a1, 32);
    a2 += __shfl_xor(a2, 16); a2 += __shfl_xor(a2, 32);
    a3 += __shfl_xor(a3, 16); a3 += __shfl_xor(a3, 32);
    if (esub == 0) {
        float4 bv = ((const float4*)headb)[l16];
        float4 o;
        o.x = fmaf(a0, inv, bv.x);
        o.y = fmaf(a1, inv, bv.y);
        o.z = fmaf(a2, inv, bv.z);
        o.w = fmaf(a3, inv, bv.w);
        ((float4*)outv)[(size_t)n * 16 + l16] = o;
    }
}

extern "C" void kernel_launch(void* const* d_in, const int* in_sizes, int n_in,
                              void* d_out, int out_size, void* d_ws, size_t ws_size,
                              hipStream_t stream) {
    const float* x     = (const float*)d_in[0];
    const int*   ei    = (const int*)d_in[1];
    const float* W1    = (const float*)d_in[2];
    const float* attn1 = (const float*)d_in[3];
    const float* W2    = (const float*)d_in[4];
    const float* attn2 = (const float*)d_in[5];
    const float* headW = (const float*)d_in[6];
    const float* headb = (const float*)d_in[7];
    float* out = (float*)d_out;

    char* ws = (char*)d_ws;
    size_t o = 0;
    auto alloc = [&](size_t bytes) -> void* {
        o = (o + 255) & ~(size_t)255;
        void* p = ws + o;
        o += bytes;
        return p;
    };
    unsigned*       h1b    = (unsigned*)alloc((size_t)N_NODES * 128 * 2);
    unsigned*       out1b  = (unsigned*)alloc((size_t)N_NODES * 128 * 2);  // bf16
    unsigned*       v2b    = (unsigned*)alloc((size_t)N_NODES * 64 * 2);   // bf16, post-head
    float*          e1s    = (float*)alloc((size_t)N_NODES * 4 * 4);
    float*          e1d    = (float*)alloc((size_t)N_NODES * 4 * 4);
    float*          e2s    = (float*)alloc((size_t)N_NODES * 4);
    float*          e2d    = (float*)alloc((size_t)N_NODES * 4);
    int*            off    = (int*)alloc((size_t)(N_NODES + 1) * 4);
    unsigned short* srcs   = (unsigned short*)alloc((size_t)E_TOT * 2);
    unsigned*       Btg    = (unsigned*)alloc((size_t)128 * 64 * 4);   // W1^T bf16
    unsigned*       Wctg   = (unsigned*)alloc((size_t)64 * 64 * 4);    // (W2@headW)^T bf16
    float*          av     = (float*)alloc((size_t)256 * 4);           // W2@a_l | W2@a_r
    int*            hist2d = (int*)alloc((size_t)NBUCK * PBLK * 4);    // [bucket][blk]
    int*            off2d  = (int*)alloc((size_t)NBUCK * PBLK * 4);
    int*            bucktot = (int*)alloc((size_t)NBUCK * 4);
    unsigned*       part   = (unsigned*)alloc((size_t)E_TOT * 4);      // src | collow<<16

    // prep (1 launch): W1^T bf16, Wc=(W2@headW)^T bf16, av vectors
    k_prep<<<193, 128, 0, stream>>>(W1, W2, attn2, headW, Btg, Wctg, av);

    // fused: gemm1 MFMA (+attn1 epilogue) || P1 bucket histogram (LDS atomics only)
    k_gemm1_p1<<<G1_BLOCKS + PBLK, 256, 0, stream>>>(
        x, Btg, attn1, (uint2*)h1b, e1s, e1d, ei, hist2d);

    // CSR build (1 cooperative launch replaces p2a/p3/p4)
    {
        void* csr_args[] = {(void*)&ei, (void*)&hist2d, (void*)&off2d, (void*)&bucktot,
                            (void*)&part, (void*)&off, (void*)&srcs};
        (void)hipLaunchCooperativeKernel((void*)k_csr, dim3(PBLK), dim3(512),
                                         csr_args, 0, stream);
    }

    // layer 1 aggregate (writes bf16 out1b + layer-2 scores e2s/e2d)
    k_agg1<<<N_NODES / 4, 256, 0, stream>>>(h1b, e1s, e1d, off, srcs, av, out1b, e2s, e2d);

    // v2 = out1b @ (W2@headW)  (bf16 MFMA)
    k_gemmv<<<(N_NODES + 63) / 64, 256, 0, stream>>>(out1b, Wctg, (uint2*)v2b);

    // final: aggregate v2b + bias -> out
    k_agg2f<<<N_NODES / 4, 256, 0, stream>>>(v2b, e2s, e2d, off, srcs, headb, out);
}

// Round 8
// 205.305 us; speedup vs baseline: 1.6211x; 1.6211x over previous
//
#include <hip/hip_runtime.h>
#include <math.h>

#define N_NODES 50000
#define E_RAW 800000
#define E_TOT 850000
#define NEG_SLOPE 0.2f
#define G1_BLOCKS ((N_NODES + 63) / 64)          // gemm1 MFMA part: BM=64, 256 thr
#define NBUCK 391                                // ceil(50000 / 128) col-buckets
#define EPB 2048                                 // edges per partition block
#define PBLK ((E_TOT + EPB - 1) / EPB)           // 416 partition blocks

typedef __attribute__((ext_vector_type(8))) short bf16x8;
typedef __attribute__((ext_vector_type(4))) float f32x4;

__device__ __forceinline__ float lrelu(float a) { return a > 0.f ? a : NEG_SLOPE * a; }

__device__ __forceinline__ unsigned f2bf(float f) {
    unsigned u = __float_as_uint(f);
    return (u + 0x7fff + ((u >> 16) & 1)) >> 16;
}
__device__ __forceinline__ unsigned pack2(float a, float b) {
    return f2bf(a) | (f2bf(b) << 16);
}
__device__ __forceinline__ float bflo(unsigned p) { return __uint_as_float(p << 16); }
__device__ __forceinline__ float bfhi(unsigned p) { return __uint_as_float(p & 0xffff0000u); }

// ---------------- prep (combined): W1^T bf16, Wc=(W2@headW)^T bf16, av=W2@attn2 halves ----
__global__ void k_prep(const float* __restrict__ W1, const float* __restrict__ W2,
                       const float* __restrict__ attn2, const float* __restrict__ headW,
                       unsigned* __restrict__ Btg, unsigned* __restrict__ Wctg,
                       float* __restrict__ av) {
    int b = blockIdx.x, t = threadIdx.x;   // 193 blocks x 128 thr
    if (b < 128) {
        if (t < 64) Btg[b * 64 + t] = pack2(W1[(2 * t) * 128 + b], W1[(2 * t + 1) * 128 + b]);
    } else if (b < 192) {
        if (t < 64) {
            int f = b - 128, q = t;
            float s0 = 0.f, s1 = 0.f;
            for (int j = 0; j < 64; ++j) {
                float hw = headW[j * 64 + f];
                s0 = fmaf(W2[(2 * q) * 64 + j], hw, s0);
                s1 = fmaf(W2[(2 * q + 1) * 64 + j], hw, s1);
            }
            Wctg[f * 64 + q] = pack2(s0, s1);
        }
    } else {
        int k = t;                          // 0..127
        float sl = 0.f, sr = 0.f;
        for (int j = 0; j < 64; ++j) {
            float w = W2[k * 64 + j];
            sl = fmaf(w, attn2[j], sl);
            sr = fmaf(w, attn2[64 + j], sr);
        }
        av[k] = sl; av[128 + k] = sr;
    }
}

// ---------------- FUSED: gemm1 MFMA (blocks < G1) || P1 bucket histogram ----------------
__global__ void k_gemm1_p1(const float* __restrict__ A, const unsigned* __restrict__ Btg,
                           const float* __restrict__ aux, uint2* __restrict__ C,
                           float* __restrict__ es, float* __restrict__ ed,
                           const int* __restrict__ ei, int* __restrict__ hist2d) {
    __shared__ unsigned As[64 * 64];   // 16 KB (gemm tile; P1 reuses first 1.6KB as int hist)
    if (blockIdx.x >= G1_BLOCKS) {
        // ---- P1 body: bucket histogram, LDS atomics only ----
        int blk = blockIdx.x - G1_BLOCKS;
        int* h = (int*)As;
        for (int i = threadIdx.x; i < NBUCK; i += 256) h[i] = 0;
        __syncthreads();
        int base = blk * EPB;
        for (int i = threadIdx.x; i < EPB; i += 256) {
            int e = base + i;
            if (e >= E_TOT) break;
            int col = (e < E_RAW) ? ei[E_RAW + e] : (e - E_RAW);
            atomicAdd(&h[col >> 7], 1);
        }
        __syncthreads();
        for (int i = threadIdx.x; i < NBUCK; i += 256) hist2d[i * PBLK + blk] = h[i];
        return;
    }
    // ---- gemm1 MFMA body ----
    int t = threadIdx.x;
    int m0 = blockIdx.x * 64;
    int rows = min(64, N_NODES - m0);
    const float4* A4 = (const float4*)(A + (size_t)m0 * 128);
    for (int i = t; i < rows * 32; i += 256) {
        int row = i >> 5, k4 = i & 31;
        float4 v = A4[i];
        int byte = (k4 * 8) ^ ((row & 7) << 4);
        unsigned* p = &As[row * 64 + (byte >> 2)];
        p[0] = pack2(v.x, v.y);
        p[1] = pack2(v.z, v.w);
    }
    __syncthreads();
    int lane = t & 63, wave = t >> 6;
    int r15 = lane & 15, g = lane >> 4;
    int arow = wave * 16 + r15;
    f32x4 acc[8];
#pragma unroll
    for (int i = 0; i < 8; ++i) acc[i] = (f32x4){0.f, 0.f, 0.f, 0.f};
    const char* Abase = (const char*)As + arow * 256;
    int swz = (arow & 7) << 4;
    const char* Bbase = (const char*)Btg;
#pragma unroll
    for (int s = 0; s < 4; ++s) {
        bf16x8 xf = *(const bf16x8*)(Abase + ((64 * s + 16 * g) ^ swz));
#pragma unroll
        for (int tt = 0; tt < 8; ++tt) {
            bf16x8 wf = *(const bf16x8*)(Bbase + ((16 * tt + r15) * 256 + 64 * s + 16 * g));
            acc[tt] = __builtin_amdgcn_mfma_f32_16x16x32_bf16(wf, xf, acc[tt], 0, 0, 0);
        }
    }
    int grow = m0 + arow;
    bool valid = (arow < rows);
    if (valid) {
        uint2* C2 = C + (size_t)grow * 32;
#pragma unroll
        for (int tt = 0; tt < 8; ++tt) {
            uint2 v; v.x = pack2(acc[tt][0], acc[tt][1]); v.y = pack2(acc[tt][2], acc[tt][3]);
            C2[4 * tt + g] = v;
        }
    }
    float ps0 = 0.f, ps1 = 0.f, ps2 = 0.f, ps3 = 0.f;
    float pd0 = 0.f, pd1 = 0.f, pd2 = 0.f, pd3 = 0.f;
#pragma unroll
    for (int tt = 0; tt < 8; ++tt) {
        int h = tt >> 1;
        int fin = 16 * (tt & 1) + 4 * g;
        float4 alv = *(const float4*)(aux + h * 64 + fin);
        float4 arv = *(const float4*)(aux + h * 64 + 32 + fin);
        float s4 = acc[tt][0] * alv.x + acc[tt][1] * alv.y + acc[tt][2] * alv.z + acc[tt][3] * alv.w;
        float d4 = acc[tt][0] * arv.x + acc[tt][1] * arv.y + acc[tt][2] * arv.z + acc[tt][3] * arv.w;
        if (h == 0) { ps0 += s4; pd0 += d4; }
        else if (h == 1) { ps1 += s4; pd1 += d4; }
        else if (h == 2) { ps2 += s4; pd2 += d4; }
        else { ps3 += s4; pd3 += d4; }
    }
#pragma unroll
    for (int mask = 16; mask <= 32; mask <<= 1) {
        ps0 += __shfl_xor(ps0, mask); ps1 += __shfl_xor(ps1, mask);
        ps2 += __shfl_xor(ps2, mask); ps3 += __shfl_xor(ps3, mask);
        pd0 += __shfl_xor(pd0, mask); pd1 += __shfl_xor(pd1, mask);
        pd2 += __shfl_xor(pd2, mask); pd3 += __shfl_xor(pd3, mask);
    }
    if (valid) {
        float psg = (g == 0) ? ps0 : (g == 1) ? ps1 : (g == 2) ? ps2 : ps3;
        float pdg = (g == 0) ? pd0 : (g == 1) ? pd1 : (g == 2) ? pd2 : pd3;
        es[grow * 4 + g] = psg;
        ed[grow * 4 + g] = pdg;
    }
}

// ---------------- P2a: per-bucket scan over partition blocks ----------------
__global__ void k_p2a(const int* __restrict__ hist2d, int* __restrict__ off2d,
                      int* __restrict__ bucktot) {
    __shared__ int sh[512];
    int b = blockIdx.x, t = threadIdx.x;
    int v = (t < PBLK) ? hist2d[b * PBLK + t] : 0;
    sh[t] = v;
    __syncthreads();
    for (int ofs = 1; ofs < 512; ofs <<= 1) {
        int u = (t >= ofs) ? sh[t - ofs] : 0;
        __syncthreads();
        sh[t] += u;
        __syncthreads();
    }
    if (t < PBLK) off2d[b * PBLK + t] = sh[t] - v;
    if (t == 511) bucktot[b] = sh[511];
}

// ---------------- P3: partition edges into bucket-grouped part[] ----------------
__global__ void k_p3(const int* __restrict__ ei, const int* __restrict__ off2d,
                     const int* __restrict__ bucktot, unsigned* __restrict__ part) {
    __shared__ int sh[512];
    __shared__ int h[NBUCK];
    __shared__ int basebuf[NBUCK];
    int blk = blockIdx.x, t = threadIdx.x;
    int v = (t < NBUCK) ? bucktot[t] : 0;
    sh[t] = v;
    if (t < NBUCK) h[t] = 0;
    __syncthreads();
    for (int ofs = 1; ofs < 512; ofs <<= 1) {
        int u = (t >= ofs) ? sh[t - ofs] : 0;
        __syncthreads();
        sh[t] += u;
        __syncthreads();
    }
    if (t < NBUCK) basebuf[t] = (sh[t] - v) + off2d[t * PBLK + blk];
    __syncthreads();
    int base = blk * EPB;
    for (int i = t; i < EPB; i += 512) {
        int e = base + i;
        if (e >= E_TOT) break;
        int col, src;
        if (e < E_RAW) { col = ei[E_RAW + e]; src = ei[e]; }
        else { col = src = e - E_RAW; }
        int b = col >> 7;
        int lr = atomicAdd(&h[b], 1);
        part[basebuf[b] + lr] = (unsigned)src | ((unsigned)(col & 127) << 16);
    }
}

// ---------------- P4: per-bucket col histogram + scan -> off[] and srcs[] ----------------
__global__ void k_p4(const unsigned* __restrict__ part, const int* __restrict__ bucktot,
                     int* __restrict__ off, unsigned short* __restrict__ srcs) {
    __shared__ int sh[512];
    __shared__ int h[128];
    __shared__ int colofs[128];
    __shared__ int s0sh, s1sh;
    int b = blockIdx.x, t = threadIdx.x;
    int v = (t < NBUCK) ? bucktot[t] : 0;
    sh[t] = v;
    if (t < 128) h[t] = 0;
    __syncthreads();
    for (int ofs = 1; ofs < 512; ofs <<= 1) {
        int u = (t >= ofs) ? sh[t - ofs] : 0;
        __syncthreads();
        sh[t] += u;
        __syncthreads();
    }
    if (t == 0) { s1sh = sh[b]; s0sh = sh[b] - bucktot[b]; }
    __syncthreads();
    int s0 = s0sh, s1 = s1sh;
    for (int i = s0 + t; i < s1; i += 512) atomicAdd(&h[part[i] >> 16], 1);
    __syncthreads();
    if (t == 0) {
        int acc = 0;
        for (int c = 0; c < 128; ++c) { colofs[c] = acc; acc += h[c]; }
    }
    __syncthreads();
    int colbase = b * 128, ncols = min(128, N_NODES - colbase);
    if (t < ncols) off[colbase + t] = s0 + colofs[t];
    if (b == NBUCK - 1 && t == 0) off[N_NODES] = s1;
    if (t < 128) h[t] = colofs[t];     // reuse as cursors
    __syncthreads();
    for (int i = s0 + t; i < s1; i += 512) {
        unsigned u = part[i];
        int c = u >> 16;
        int slot = atomicAdd(&h[c], 1);
        srcs[s0 + slot] = (unsigned short)(u & 0xffffu);
    }
}

// ---------------- GEMMV MFMA: v2 = out1b(bf16) @ Wc, K=128, N=64 (no epilogue) ----------------
__global__ void k_gemmv(const unsigned* __restrict__ A, const unsigned* __restrict__ Wctg,
                        uint2* __restrict__ C) {
    __shared__ unsigned As[64 * 64];   // 16 KB: 64 rows x 128 bf16, swizzled
    int t = threadIdx.x;
    int m0 = blockIdx.x * 64;
    int rows = min(64, N_NODES - m0);
    const uint4* A4 = (const uint4*)(A + (size_t)m0 * 64);
    for (int i = t; i < rows * 16; i += 256) {
        int row = i >> 4, q = i & 15;
        uint4 v = A4[i];
        int byte = (q * 16) ^ ((row & 7) << 4);
        unsigned* p = &As[row * 64 + (byte >> 2)];
        p[0] = v.x; p[1] = v.y; p[2] = v.z; p[3] = v.w;
    }
    __syncthreads();
    int lane = t & 63, wave = t >> 6;
    int r15 = lane & 15, g = lane >> 4;
    int arow = wave * 16 + r15;
    f32x4 acc[4];
#pragma unroll
    for (int i = 0; i < 4; ++i) acc[i] = (f32x4){0.f, 0.f, 0.f, 0.f};
    const char* Abase = (const char*)As + arow * 256;
    int swz = (arow & 7) << 4;
    const char* Bbase = (const char*)Wctg;
#pragma unroll
    for (int s = 0; s < 4; ++s) {
        bf16x8 xf = *(const bf16x8*)(Abase + ((64 * s + 16 * g) ^ swz));
#pragma unroll
        for (int tt = 0; tt < 4; ++tt) {
            bf16x8 wf = *(const bf16x8*)(Bbase + ((16 * tt + r15) * 256 + 64 * s + 16 * g));
            acc[tt] = __builtin_amdgcn_mfma_f32_16x16x32_bf16(wf, xf, acc[tt], 0, 0, 0);
        }
    }
    int grow = m0 + arow;
    if (arow < rows) {
        uint2* C2 = C + (size_t)grow * 16;
#pragma unroll
        for (int tt = 0; tt < 4; ++tt) {
            uint2 v; v.x = pack2(acc[tt][0], acc[tt][1]); v.y = pack2(acc[tt][2], acc[tt][3]);
            C2[4 * tt + g] = v;
        }
    }
}

// ---------------- layer-1 fused softmax+aggregate + layer-2 score epilogue ----------------
// Latency-overlapped: row gathers (depend only on srcj) issue BEFORE the es-gather/exp
// chain, so the two ~500cy memory chains run in parallel instead of serially.
__global__ void k_agg1(const unsigned* __restrict__ h1b, const float* __restrict__ es,
                       const float* __restrict__ ed, const int* __restrict__ off,
                       const unsigned short* __restrict__ srcs, const float* __restrict__ av,
                       unsigned* __restrict__ out1,
                       float* __restrict__ e2s, float* __restrict__ e2d) {
    int n = blockIdx.x * (blockDim.x >> 6) + (threadIdx.x >> 6);
    int lane = threadIdx.x & 63;
    if (n >= N_NODES) return;
    int myh = lane & 3;           // head for w-compute phase
    int jj = lane >> 2;           // edge slot (0..15) for w-compute
    float edh = ed[n * 4 + myh];
    int s = off[n], e = off[n + 1];
    int l16 = lane & 15;          // feature block: features 8*l16 .. 8*l16+7
    int esub = lane >> 4;         // edge subgroup 0..3
    int hcL = l16 >> 2;           // head owning this lane's features
    float acc[8];
#pragma unroll
    for (int i = 0; i < 8; ++i) acc[i] = 0.f;
    float psum = 0.f;
    for (int base = s; base < e; base += 16) {
        int cnt = e - base;       // wave-uniform
        int srcj = 0;
        if (jj < cnt) srcj = srcs[base + jj];
        // 1) shuffle src indices and ISSUE the row gathers first
        int src4[4];
#pragma unroll
        for (int q = 0; q < 4; ++q) src4[q] = __shfl(srcj, (4 * q + esub) * 4);
        uint4 pv4[4];
#pragma unroll
        for (int q = 0; q < 4; ++q)
            pv4[q] = *((const uint4*)(h1b + (size_t)src4[q] * 64 + l16 * 4));
        // 2) es-gather + exp chain overlaps the row-gather latency
        float w = 0.f;
        if (jj < cnt) w = __expf(lrelu(es[srcj * 4 + myh] + edh));
        psum += w;
        float wv4[4];
#pragma unroll
        for (int q = 0; q < 4; ++q) wv4[q] = __shfl(w, (4 * q + esub) * 4 + hcL);
        // 3) FMAs
#pragma unroll
        for (int q = 0; q < 4; ++q) {
            float wv = wv4[q];
            acc[0] = fmaf(bflo(pv4[q].x), wv, acc[0]);
            acc[1] = fmaf(bfhi(pv4[q].x), wv, acc[1]);
            acc[2] = fmaf(bflo(pv4[q].y), wv, acc[2]);
            acc[3] = fmaf(bfhi(pv4[q].y), wv, acc[3]);
            acc[4] = fmaf(bflo(pv4[q].z), wv, acc[4]);
            acc[5] = fmaf(bfhi(pv4[q].z), wv, acc[5]);
            acc[6] = fmaf(bflo(pv4[q].w), wv, acc[6]);
            acc[7] = fmaf(bfhi(pv4[q].w), wv, acc[7]);
        }
    }
    // per-head softmax denom: sum over edge slots (bits 2-5), heads (bits 0-1) preserved
#pragma unroll
    for (int mask = 4; mask <= 32; mask <<= 1) psum += __shfl_xor(psum, mask);
    float inv = 1.f / __shfl(psum, hcL);
    // reduce the 4 edge-subgroups
#pragma unroll
    for (int i = 0; i < 8; ++i) {
        acc[i] += __shfl_xor(acc[i], 16);
        acc[i] += __shfl_xor(acc[i], 32);
    }
    float o[8];
#pragma unroll
    for (int i = 0; i < 8; ++i) o[i] = fmaxf(acc[i] * inv, 0.f);
    if (esub == 0) {
        uint4 ov;
        ov.x = pack2(o[0], o[1]);
        ov.y = pack2(o[2], o[3]);
        ov.z = pack2(o[4], o[5]);
        ov.w = pack2(o[6], o[7]);
        *((uint4*)(out1 + (size_t)n * 64 + l16 * 4)) = ov;
    }
    // layer-2 attention scores (all lanes hold full o for their 8 features)
    float4 vl0 = *(const float4*)(av + 8 * l16);
    float4 vl1 = *(const float4*)(av + 8 * l16 + 4);
    float4 vr0 = *(const float4*)(av + 128 + 8 * l16);
    float4 vr1 = *(const float4*)(av + 128 + 8 * l16 + 4);
    float pl = o[0] * vl0.x + o[1] * vl0.y + o[2] * vl0.z + o[3] * vl0.w
             + o[4] * vl1.x + o[5] * vl1.y + o[6] * vl1.z + o[7] * vl1.w;
    float pr = o[0] * vr0.x + o[1] * vr0.y + o[2] * vr0.z + o[3] * vr0.w
             + o[4] * vr1.x + o[5] * vr1.y + o[6] * vr1.z + o[7] * vr1.w;
#pragma unroll
    for (int mask = 1; mask <= 8; mask <<= 1) {
        pl += __shfl_xor(pl, mask);
        pr += __shfl_xor(pr, mask);
    }
    if (lane == 0) { e2s[n] = pl; e2d[n] = pr; }
}

// ---------------- layer-2 aggregate (final): gather v2b rows + bias -> out ----------------
// Same latency-overlap reorder as agg1.
__global__ void k_agg2f(const unsigned* __restrict__ v2b, const float* __restrict__ es,
                        const float* __restrict__ ed, const int* __restrict__ off,
                        const unsigned short* __restrict__ srcs,
                        const float* __restrict__ headb, float* __restrict__ outv) {
    int n = blockIdx.x * 4 + (threadIdx.x >> 6);   // grid is exactly N_NODES/4
    int lane = threadIdx.x & 63;
    float edv = ed[n];
    int s = off[n], e = off[n + 1];
    int l16 = lane & 15;          // feature block: features 4*l16 .. 4*l16+3
    int esub = lane >> 4;         // edge subgroup 0..3
    const uint2* gp = (const uint2*)v2b;
    float a0 = 0.f, a1 = 0.f, a2 = 0.f, a3 = 0.f, psum = 0.f;
    for (int base = s; base < e; base += 16) {
        int cnt = e - base;        // wave-uniform
        int srcj = 0;
        if (lane < 16 && lane < cnt) srcj = srcs[base + lane];
        int src4[4];
#pragma unroll
        for (int q = 0; q < 4; ++q) src4[q] = __shfl(srcj, 4 * q + esub);
        uint2 pv4[4];
#pragma unroll
        for (int q = 0; q < 4; ++q) pv4[q] = gp[(size_t)src4[q] * 16 + l16];
        float w = 0.f;
        if (lane < 16 && lane < cnt) w = __expf(lrelu(es[srcj] + edv));
        psum += w;
        float wv4[4];
#pragma unroll
        for (int q = 0; q < 4; ++q) wv4[q] = __shfl(w, 4 * q + esub);
#pragma unroll
        for (int q = 0; q < 4; ++q) {
            a0 = fmaf(bflo(pv4[q].x), wv4[q], a0);
            a1 = fmaf(bfhi(pv4[q].x), wv4[q], a1);
            a2 = fmaf(bflo(pv4[q].y), wv4[q], a2);
            a3 = fmaf(bfhi(pv4[q].y), wv4[q], a3);
        }
    }
#pragma unroll
    for (int mask = 1; mask <= 8; mask <<= 1) psum += __shfl_xor(psum, mask);
    float inv = 1.f / __shfl(psum, 0);
    a0 += __shfl_xor(a0, 16); a0 += __shfl_xor(a0, 32);
    a1 += __shfl_xor(a1, 16); a1 += __shfl_xor(a1, 32);
    a2 += __shfl_xor(a2, 16); a2 += __shfl_xor(a2, 32);
    a3 += __shfl_xor(a3, 16); a3 += __shfl_xor(a3, 32);
    if (esub == 0) {
        float4 bv = ((const float4*)headb)[l16];
        float4 o;
        o.x = fmaf(a0, inv, bv.x);
        o.y = fmaf(a1, inv, bv.y);
        o.z = fmaf(a2, inv, bv.z);
        o.w = fmaf(a3, inv, bv.w);
        ((float4*)outv)[(size_t)n * 16 + l16] = o;
    }
}

extern "C" void kernel_launch(void* const* d_in, const int* in_sizes, int n_in,
                              void* d_out, int out_size, void* d_ws, size_t ws_size,
                              hipStream_t stream) {
    const float* x     = (const float*)d_in[0];
    const int*   ei    = (const int*)d_in[1];
    const float* W1    = (const float*)d_in[2];
    const float* attn1 = (const float*)d_in[3];
    const float* W2    = (const float*)d_in[4];
    const float* attn2 = (const float*)d_in[5];
    const float* headW = (const float*)d_in[6];
    const float* headb = (const float*)d_in[7];
    float* out = (float*)d_out;

    char* ws = (char*)d_ws;
    size_t o = 0;
    auto alloc = [&](size_t bytes) -> void* {
        o = (o + 255) & ~(size_t)255;
        void* p = ws + o;
        o += bytes;
        return p;
    };
    unsigned*       h1b    = (unsigned*)alloc((size_t)N_NODES * 128 * 2);
    unsigned*       out1b  = (unsigned*)alloc((size_t)N_NODES * 128 * 2);  // bf16
    unsigned*       v2b    = (unsigned*)alloc((size_t)N_NODES * 64 * 2);   // bf16, post-head
    float*          e1s    = (float*)alloc((size_t)N_NODES * 4 * 4);
    float*          e1d    = (float*)alloc((size_t)N_NODES * 4 * 4);
    float*          e2s    = (float*)alloc((size_t)N_NODES * 4);
    float*          e2d    = (float*)alloc((size_t)N_NODES * 4);
    int*            off    = (int*)alloc((size_t)(N_NODES + 1) * 4);
    unsigned short* srcs   = (unsigned short*)alloc((size_t)E_TOT * 2);
    unsigned*       Btg    = (unsigned*)alloc((size_t)128 * 64 * 4);   // W1^T bf16
    unsigned*       Wctg   = (unsigned*)alloc((size_t)64 * 64 * 4);    // (W2@headW)^T bf16
    float*          av     = (float*)alloc((size_t)256 * 4);           // W2@a_l | W2@a_r
    int*            hist2d = (int*)alloc((size_t)NBUCK * PBLK * 4);    // [bucket][blk]
    int*            off2d  = (int*)alloc((size_t)NBUCK * PBLK * 4);
    int*            bucktot = (int*)alloc((size_t)NBUCK * 4);
    unsigned*       part   = (unsigned*)alloc((size_t)E_TOT * 4);      // src | collow<<16

    // prep (1 launch): W1^T bf16, Wc=(W2@headW)^T bf16, av vectors
    k_prep<<<193, 128, 0, stream>>>(W1, W2, attn2, headW, Btg, Wctg, av);

    // fused: gemm1 MFMA (+attn1 epilogue) || P1 bucket histogram (LDS atomics only)
    k_gemm1_p1<<<G1_BLOCKS + PBLK, 256, 0, stream>>>(
        x, Btg, attn1, (uint2*)h1b, e1s, e1d, ei, hist2d);

    // CSR build: separate kernels (cooperative grid.sync was 125us — reverted)
    k_p2a<<<NBUCK, 512, 0, stream>>>(hist2d, off2d, bucktot);
    k_p3<<<PBLK, 512, 0, stream>>>(ei, off2d, bucktot, part);
    k_p4<<<NBUCK, 512, 0, stream>>>(part, bucktot, off, srcs);

    // layer 1 aggregate (writes bf16 out1b + layer-2 scores e2s/e2d)
    k_agg1<<<N_NODES / 4, 256, 0, stream>>>(h1b, e1s, e1d, off, srcs, av, out1b, e2s, e2d);

    // v2 = out1b @ (W2@headW)  (bf16 MFMA)
    k_gemmv<<<(N_NODES + 63) / 64, 256, 0, stream>>>(out1b, Wctg, (uint2*)v2b);

    // final: aggregate v2b + bias -> out
    k_agg2f<<<N_NODES / 4, 256, 0, stream>>>(v2b, e2s, e2d, off, srcs, headb, out);
}